// Round 6
// baseline (534.462 us; speedup 1.0000x reference)
//
#include <hip/hip_runtime.h>
#include <hip/hip_bf16.h>

#define BB 256
#define TT 512
#define EE 300
#define G4 200     // 4*H1
#define BKP 20     // proj stage depth (300 = 15*20)
#define NST 15

// permuted gate col: G1 column jp corresponds to W row (jp&3)*50 + (jp>>2).

__device__ __forceinline__ float sigm(float x) {
    return __builtin_amdgcn_rcpf(1.f + __builtin_amdgcn_exp2f(-1.442695040888963f * x));
}
__device__ __forceinline__ float tanh_(float x) {
    float t = __builtin_amdgcn_exp2f(2.885390081777927f * x);   // e^(2x)
    return 1.f - 2.f * __builtin_amdgcn_rcpf(t + 1.f);
}

// quad broadcast via DPP: all 4 lanes of a quad get quad-lane C's value
template <int C>
__device__ __forceinline__ float qb(float v) {
    return __int_as_float(__builtin_amdgcn_mov_dpp(__float_as_int(v), C, 0xF, 0xF, true));
}

// ---------------------------------------------------------------------------
// K1: permuted transpose W_ih1 [200,300] -> Wt [300][200] (unpadded, linear)
__global__ void wtrans_kernel(const float* __restrict__ W, float* __restrict__ Wt) {
    int e = blockIdx.x;        // 0..299
    int j = threadIdx.x;       // 0..255
    if (j < G4) {
        int row = (j & 3) * 50 + (j >> 2);
        Wt[e * G4 + j] = W[row * EE + e];
    }
}

// ---------------------------------------------------------------------------
// K2: G1[bb][t][jp] = b1[row(jp)] + emb[x[b][t]] . W_ih1[row(jp)]
// 64 t-rows x 200 cols per block; W staged via regs -> 16KB LDS, pipelined.
__device__ __forceinline__ float f4get(const float4& v, int u) {
    return u == 0 ? v.x : u == 1 ? v.y : u == 2 ? v.z : v.w;
}

__global__ __launch_bounds__(256) void proj_kernel(
    const int* __restrict__ x, const int* __restrict__ lengths,
    const float* __restrict__ emb, const float* __restrict__ b1,
    const float* __restrict__ Wt, float* __restrict__ G1, int b0)
{
    const int b  = b0 + blockIdx.y;
    const int t0 = blockIdx.x * 64;
    const int len = lengths[b];
    if (t0 >= len) return;                       // uniform: whole tile padding

    const int tid = threadIdx.x;
    const int rg  = tid >> 5;                    // rows rg*8 .. rg*8+7
    const int jg  = tid & 31;                    // col group; valid if jg<25
    const bool active = (jg < 25);

    __shared__ float4 Ws4[BKP * 50];             // 16 KB

    const float* er[8];
    #pragma unroll
    for (int q = 0; q < 8; ++q)
        er[q] = emb + (size_t)x[b * TT + t0 + rg * 8 + q] * EE;

    float acc[8][8];
    {
        float bv[8];
        #pragma unroll
        for (int k = 0; k < 8; ++k) {
            int c = (k < 4) ? (4 * jg + k) : (96 + 4 * jg + k);
            bv[k] = active ? b1[(c & 3) * 50 + (c >> 2)] : 0.f;
        }
        #pragma unroll
        for (int q = 0; q < 8; ++q)
            #pragma unroll
            for (int k = 0; k < 8; ++k) acc[q][k] = bv[k];
    }

    const float4* Wt4 = (const float4*)Wt;       // 300*50 float4, fully linear

    // stage-0 W into regs
    float4 st[4];
    #pragma unroll
    for (int j = 0; j < 4; ++j) {
        int i = tid + 256 * j;
        if (i < BKP * 50) st[j] = Wt4[i];
    }

    // 2-deep A prefetch
    float4 avn[8], avn2[8];
    #pragma unroll
    for (int q = 0; q < 8; ++q) avn[q]  = *(const float4*)(er[q]);
    #pragma unroll
    for (int q = 0; q < 8; ++q) avn2[q] = *(const float4*)(er[q] + 4);

    for (int s = 0; s < NST; ++s) {
        if (s) {                                  // readers of prev stage done
            asm volatile("" ::: "memory");
            __builtin_amdgcn_s_barrier();
        }
        asm volatile("s_waitcnt vmcnt(0)" ::: "memory");   // st arrived
        #pragma unroll
        for (int j = 0; j < 4; ++j) {
            int i = tid + 256 * j;
            if (i < BKP * 50) Ws4[i] = st[j];
        }
        if (s + 1 < NST) {                        // fetch next stage during compute
            const float4* src = Wt4 + (size_t)(s + 1) * BKP * 50;
            #pragma unroll
            for (int j = 0; j < 4; ++j) {
                int i = tid + 256 * j;
                if (i < BKP * 50) st[j] = src[i];
            }
        }
        asm volatile("s_waitcnt lgkmcnt(0)" ::: "memory");
        __builtin_amdgcn_s_barrier();
        __builtin_amdgcn_sched_barrier(0);

        #pragma unroll
        for (int kk = 0; kk < BKP / 4; ++kk) {
            float4 av[8];
            #pragma unroll
            for (int q = 0; q < 8; ++q) { av[q] = avn[q]; avn[q] = avn2[q]; }
            int en2 = s * BKP + kk * 4 + 8;       // 2 slices ahead
            if (en2 > EE - 4) en2 = EE - 4;
            #pragma unroll
            for (int q = 0; q < 8; ++q)
                avn2[q] = *(const float4*)(er[q] + en2);
            if (active) {
                #pragma unroll
                for (int u = 0; u < 4; ++u) {
                    float4 w0 = Ws4[(kk * 4 + u) * 50 + jg];
                    float4 w1 = Ws4[(kk * 4 + u) * 50 + 25 + jg];
                    #pragma unroll
                    for (int q = 0; q < 8; ++q) {
                        float a = f4get(av[q], u);
                        acc[q][0] = fmaf(a, w0.x, acc[q][0]);
                        acc[q][1] = fmaf(a, w0.y, acc[q][1]);
                        acc[q][2] = fmaf(a, w0.z, acc[q][2]);
                        acc[q][3] = fmaf(a, w0.w, acc[q][3]);
                        acc[q][4] = fmaf(a, w1.x, acc[q][4]);
                        acc[q][5] = fmaf(a, w1.y, acc[q][5]);
                        acc[q][6] = fmaf(a, w1.z, acc[q][6]);
                        acc[q][7] = fmaf(a, w1.w, acc[q][7]);
                    }
                }
            }
        }
    }

    if (active) {
        float* gbase = G1 + ((size_t)blockIdx.y * TT + t0) * G4;
        #pragma unroll
        for (int q = 0; q < 8; ++q) {
            float* gp = gbase + (size_t)(rg * 8 + q) * G4;
            *(float4*)(gp + 4 * jg)       = make_float4(acc[q][0], acc[q][1], acc[q][2], acc[q][3]);
            *(float4*)(gp + 100 + 4 * jg) = make_float4(acc[q][4], acc[q][5], acc[q][6], acc[q][7]);
        }
    }
}

// ---------------------------------------------------------------------------
// K3: recurrence. One block (512 thr = 8 waves) per batch element.
// 8-lane group = one unit: sub=tid&7 -> gate g=sub&3, half=sub>>2.
// Each thread: 28-elem half-dot; halves combined via shfl_xor(4); gates
// broadcast via quad DPP. One barrier/step.
//   tid 0..399  : LSTM1 unit u=tid>>3 (0..49)
//   tid 400..479: LSTM2 unit u=(tid>>3)-50 (0..9), lags one step
//   tid 480..511: inert (zero weights)
// hs[2][72]: h1 at [0..49] (pad to 55), h2 at [56..65] (pad to 71).
__global__ __launch_bounds__(512, 1) void lstm_kernel(
    const int* __restrict__ lengths,
    const float* __restrict__ W_hh1, const float* __restrict__ W_ih2,
    const float* __restrict__ W_hh2, const float* __restrict__ b2,
    const float* __restrict__ fc1w, const float* __restrict__ fc1b,
    const float* __restrict__ fc2w, const float* __restrict__ fc2b,
    const float* __restrict__ G1, float* __restrict__ out, int b0)
{
    const int bb  = blockIdx.x;
    const int b   = b0 + bb;
    const int tid = threadIdx.x;
    const int len = lengths[b];

    __shared__ __align__(16) float hs[2][72];
    __shared__ __align__(16) float hfin[12];
    __shared__ float zbuf[10];

    if (tid < 72) { hs[0][tid] = 0.f; hs[1][tid] = 0.f; }

    const bool isL1 = (tid < 400);
    const bool isL2 = (tid >= 400 && tid < 480);
    const int  grp  = tid >> 3;
    const int  sub  = tid & 7;
    const int  g    = sub & 3;
    const int  half = sub >> 2;

    float wreg[28];                 // half of W_hh1 row | half of W_ih2 row
    float wregb[12];                // L2 half0: W_hh2 row
    #pragma unroll
    for (int k = 0; k < 28; ++k) wreg[k] = 0.f;
    #pragma unroll
    for (int k = 0; k < 12; ++k) wregb[k] = 0.f;
    float base2 = 0.f;

    if (isL1) {
        int row = g * 50 + grp;
        const float* wp = W_hh1 + row * 50 + half * 28;
        int n = half ? 22 : 28;
        for (int k = 0; k < 28; ++k) wreg[k] = (k < n) ? wp[k] : 0.f;
    } else if (isL2) {
        int u = grp - 50;
        int row = g * 10 + u;
        const float* wp = W_ih2 + row * 50 + half * 28;
        int n = half ? 22 : 28;
        for (int k = 0; k < 28; ++k) wreg[k] = (k < n) ? wp[k] : 0.f;
        if (half == 0) {
            const float* wp2 = W_hh2 + row * 10;
            #pragma unroll
            for (int k = 0; k < 10; ++k) wregb[k] = wp2[k];
            base2 = b2[row];
        }
    }

    const bool gld  = isL1 && (half == 0);        // G1-loading lanes
    const int  gcol = gld ? (4 * grp + g) : 0;    // permuted column jp
    const bool wr   = (sub == 0) && (tid < 480);
    const int  slot = isL1 ? grp : (56 + grp - 50);

    float h1v[28], h2v[12];
    #pragma unroll
    for (int k = 0; k < 28; ++k) h1v[k] = 0.f;
    #pragma unroll
    for (int k = 0; k < 12; ++k) h2v[k] = 0.f;

    float c = 0.f;
    const float* g1p = G1 + (size_t)bb * TT * G4;
    float p0 = 0.f, p1 = 0.f, p2 = 0.f;          // 3-deep G1 prefetch
    if (gld) {
        int t1 = (1 < len) ? 1 : len - 1;
        int t2 = (2 < len) ? 2 : len - 1;
        p0 = g1p[gcol];
        p1 = g1p[(size_t)t1 * G4 + gcol];
        p2 = g1p[(size_t)t2 * G4 + gcol];
    }

    __syncthreads();                              // LDS zero-init visible

    for (int i = 0; i < len; ++i) {
        float base = gld ? p0 : ((isL2 && half == 0) ? base2 : 0.f);
        p0 = p1; p1 = p2;
        if (gld) {
            int tn = (i + 3 < len) ? i + 3 : len - 1;
            p2 = g1p[(size_t)tn * G4 + gcol];      // never drained
        }

        float s0 = 0.f, s1 = 0.f, s2 = 0.f, s3 = 0.f;
        #pragma unroll
        for (int m = 0; m < 7; ++m) {
            s0 = fmaf(wreg[4*m+0], h1v[4*m+0], s0);
            s1 = fmaf(wreg[4*m+1], h1v[4*m+1], s1);
            s2 = fmaf(wreg[4*m+2], h1v[4*m+2], s2);
            s3 = fmaf(wreg[4*m+3], h1v[4*m+3], s3);
        }
        #pragma unroll
        for (int m = 0; m < 3; ++m) {
            s0 = fmaf(wregb[4*m+0], h2v[4*m+0], s0);
            s1 = fmaf(wregb[4*m+1], h2v[4*m+1], s1);
            s2 = fmaf(wregb[4*m+2], h2v[4*m+2], s2);
            s3 = fmaf(wregb[4*m+3], h2v[4*m+3], s3);
        }
        float t = base + (s0 + s1) + (s2 + s3);
        float full = t + __shfl_xor(t, 4, 64);     // combine the two halves

        float gi = qb<0x00>(full);
        float gf = qb<0x55>(full);
        float gg = qb<0xAA>(full);
        float go = qb<0xFF>(full);
        float cn = sigm(gf) * c + sigm(gi) * tanh_(gg);
        float hn = sigm(go) * tanh_(cn);
        if (isL2 && i == 0) { cn = 0.f; hn = 0.f; }   // L2 lag: h2(-1)=0
        c = cn;
        if (wr) hs[i & 1][slot] = hn;

        asm volatile("s_waitcnt lgkmcnt(0)" ::: "memory");
        __builtin_amdgcn_s_barrier();
        __builtin_amdgcn_sched_barrier(0);

        // read own half of h(i) (and h2(i-1) for L2)
        const float* hb = hs[i & 1] + half * 28;
        #pragma unroll
        for (int m = 0; m < 7; ++m) {
            float4 v = *(const float4*)(hb + 4 * m);
            h1v[4*m+0] = v.x; h1v[4*m+1] = v.y;
            h1v[4*m+2] = v.z; h1v[4*m+3] = v.w;
        }
        if (tid >= 400 && tid < 480) {
            const float* hb2 = hs[i & 1] + 56;
            #pragma unroll
            for (int m = 0; m < 3; ++m) {
                float4 v = *(const float4*)(hb2 + 4 * m);
                h2v[4*m+0] = v.x; h2v[4*m+1] = v.y;
                h2v[4*m+2] = v.z; h2v[4*m+3] = v.w;
            }
        }
    }

    // ---- tail: L2 computes h2(len-1) from h1(len-1), h2(len-2)
    {
        float s0 = 0.f, s1 = 0.f, s2 = 0.f, s3 = 0.f;
        #pragma unroll
        for (int m = 0; m < 7; ++m) {
            s0 = fmaf(wreg[4*m+0], h1v[4*m+0], s0);
            s1 = fmaf(wreg[4*m+1], h1v[4*m+1], s1);
            s2 = fmaf(wreg[4*m+2], h1v[4*m+2], s2);
            s3 = fmaf(wreg[4*m+3], h1v[4*m+3], s3);
        }
        #pragma unroll
        for (int m = 0; m < 3; ++m) {
            s0 = fmaf(wregb[4*m+0], h2v[4*m+0], s0);
            s1 = fmaf(wregb[4*m+1], h2v[4*m+1], s1);
            s2 = fmaf(wregb[4*m+2], h2v[4*m+2], s2);
            s3 = fmaf(wregb[4*m+3], h2v[4*m+3], s3);
        }
        float t = ((isL2 && half == 0) ? base2 : 0.f) + (s0 + s1) + (s2 + s3);
        float full = t + __shfl_xor(t, 4, 64);
        float gi = qb<0x00>(full);
        float gf = qb<0x55>(full);
        float gg = qb<0xAA>(full);
        float go = qb<0xFF>(full);
        float cn = sigm(gf) * c + sigm(gi) * tanh_(gg);
        float hn = sigm(go) * tanh_(cn);
        if (isL2 && sub == 0) hfin[grp - 50] = hn;
    }
    __syncthreads();

    // ---- MLP head
    if (tid < 10) {
        float s = fc1b[tid];
        #pragma unroll
        for (int e = 0; e < 10; ++e) s = fmaf(fc1w[tid * 10 + e], hfin[e], s);
        zbuf[tid] = s > 0.f ? s : 0.f;
    }
    __syncthreads();
    if (tid == 0) {
        float s = fc2b[0];
        #pragma unroll
        for (int e = 0; e < 10; ++e) s = fmaf(fc2w[e], zbuf[e], s);
        out[b] = s;
    }
}

// ---------------------------------------------------------------------------
extern "C" void kernel_launch(void* const* d_in, const int* in_sizes, int n_in,
                              void* d_out, int out_size, void* d_ws, size_t ws_size,
                              hipStream_t stream)
{
    const int*   x     = (const int*)  d_in[0];
    const int*   len   = (const int*)  d_in[1];
    const float* emb   = (const float*)d_in[2];
    const float* W_ih1 = (const float*)d_in[3];
    const float* W_hh1 = (const float*)d_in[4];
    const float* b1    = (const float*)d_in[5];
    const float* W_ih2 = (const float*)d_in[6];
    const float* W_hh2 = (const float*)d_in[7];
    const float* b2    = (const float*)d_in[8];
    const float* fc1w  = (const float*)d_in[9];
    const float* fc1b  = (const float*)d_in[10];
    const float* fc2w  = (const float*)d_in[11];
    const float* fc2b  = (const float*)d_in[12];
    float* out = (float*)d_out;

    const size_t wt_bytes = (size_t)EE * G4 * sizeof(float);     // 240000
    const size_t per_b    = (size_t)TT * G4 * sizeof(float);     // 409600
    float* Wt = (float*)d_ws;
    float* G1 = (float*)((char*)d_ws + ((wt_bytes + 255) & ~255ull));

    size_t head = (wt_bytes + 255) & ~255ull;
    size_t avail = ws_size > head ? ws_size - head : 0;
    int chunk = (int)(avail / per_b);
    if (chunk < 1) chunk = 1;
    if (chunk > BB) chunk = BB;

    wtrans_kernel<<<dim3(EE), dim3(256), 0, stream>>>(W_ih1, Wt);

    for (int b0 = 0; b0 < BB; b0 += chunk) {
        int nb = (BB - b0) < chunk ? (BB - b0) : chunk;
        proj_kernel<<<dim3(TT / 64, nb), dim3(256), 0, stream>>>(
            x, len, emb, b1, Wt, G1, b0);
        lstm_kernel<<<dim3(nb), dim3(512), 0, stream>>>(
            len, W_hh1, W_ih2, W_hh2, b2, fc1w, fc1b, fc2w, fc2b, G1, out, b0);
    }
}